// Round 5
// baseline (131.072 us; speedup 1.0000x reference)
//
#include <hip/hip_runtime.h>
#include <math.h>

#define S_LEN  4096
#define NCH    64
#define TILE_S 128
#define RPT    16          // s-rows per thread (R0-vs-R1 evidence: denser is faster)
#define TY     8           // 512 threads = 8 waves
#define NQ     48          // staged quads (192 rows = 128 tile + 64 halo)
#define NQS    49          // padded quad stride (196 dw; 196%32=4 -> balanced banks)
#define WQ     20          // window quads per thread (80 rows >= 77 needed)
#define PQ     5           // preloaded quads (3-tap slack ~290cy vs ~120cy LDS lat)
#define WLEN   80          // win floats; used indices 1..77

// ---------------------------------------------------------------------------
// Round-8. R4 post-mortem: literal weights helped (+7us, cwt ~53 -> ~46) but
// remaining gap to ~24us floor persists; implied VALUBusy ~34% -> waves still
// wait 2/3 of the time on stage/barrier/per-output overhead. Prior direct A/B
// on work density (R0 RPT=16 vs R1 RPT=8, same structure) favored RPT=16 by
// ~3us. This round: RPT=16 / TILE_S=128 on top of ALL validated R4 pieces
// (constexpr literal weights -> zero in-loop s_load; transposed quad LDS ->
// 20 ds_read_b128 per thread, balanced banks; XCD swizzle). Per-output-row
// costs halve: stage instrs 30->15, barriers 1/2048-outputs -> 1/4096, halo
// read-amp 1.5 -> 1.25. LDS 50.2KB -> 3 blocks/CU (24 waves, enough per R1's
// occupancy-null). VGPR est ~90 (acc 48 + ~23 live window) < 2048/6.
// If NULL: per-block amortization is exhausted; pivot to barrier-free
// full-window-MLP direct-global next.
// ---------------------------------------------------------------------------

// ---- constexpr weight construction (compile-time) --------------------------
constexpr double cexp_(double v) {            // v in [-25, 0]
  const double LN2 = 0.6931471805599453;
  double t = v / LN2;
  int k = (int)t;
  if (t < 0.0 && (double)k != t) --k;
  double r = v - (double)k * LN2;             // r in [0, ln2)
  double term = 1.0, sum = 1.0;
  for (int n = 1; n <= 22; ++n) { term *= r / (double)n; sum += term; }
  while (k > 0) { sum *= 2.0; --k; }
  while (k < 0) { sum *= 0.5; ++k; }
  return sum;
}
constexpr double csqrt_(double a) {
  double y = a > 1.0 ? a : 1.0;
  for (int i = 0; i < 64; ++i) y = 0.5 * (y + a / y);
  return y;
}
struct Wt { float w6[62]; float w3[32]; float w1[12]; };
constexpr Wt make_weights() {
  Wt w{};
  double ip[1024] = {};
  const double delta = 10.0 / 1023.0;
  const double step  = (-5.0 + delta) + 5.0;        // == numpy x[1]-x[0]
  const double cn    = csqrt_(csqrt_(1.5707963267948966)); // (pi/2)^0.25
  double s = 0.0;
  for (int i = 0; i < 1024; ++i) {
    const double xi  = (i == 1023) ? 5.0 : ((double)i * delta - 5.0);
    const double psi = (-2.0 * xi) * cexp_(-(xi * xi)) / cn;
    s += psi;
    ip[i] = s * step;
  }
  const int as_[3] = {6, 3, 1};
  const int lf_[3] = {61, 31, 11};
  for (int si = 0; si < 3; ++si) {
    const double denom = (double)as_[si] * step;
    const float  sqa   = (float)csqrt_((double)as_[si]);
    const int    lf    = lf_[si];
    for (int t = 0; t <= lf; ++t) {
      float km1 = 0.f, kt = 0.f;
      if (t >= 1)      km1 = (float)ip[(long)(((double)(t - 1)) / denom)];
      if (t <= lf - 1) kt  = (float)ip[(long)(((double)t) / denom)];
      const float val = -sqa * (km1 - kt);
      if (si == 0) w.w6[t] = val; else if (si == 1) w.w3[t] = val; else w.w1[t] = val;
    }
  }
  return w;
}
constexpr Wt CW = make_weights();
// Template variables force compile-time folding -> inline literal operands.
template <int T> constexpr float W6 = CW.w6[T];
template <int T> constexpr float W3 = CW.w3[T];
template <int T> constexpr float W1 = CW.w1[T];

// ---- compute recursion (all indices compile-time) --------------------------
template <int T, int R>
struct FmaR {
  static __device__ __forceinline__ void run(const float (&win)[WLEN],
                                             float (&a6)[RPT], float (&a3)[RPT],
                                             float (&a1)[RPT]) {
    a6[R] = fmaf(W6<T>, win[T + R + 1], a6[R]);
    if constexpr (T >= 15 && T <= 46) a3[R] = fmaf(W3<T - 15>, win[T + R + 1], a3[R]);
    if constexpr (T >= 25 && T <= 36) a1[R] = fmaf(W1<T - 25>, win[T + R + 1], a1[R]);
    FmaR<T, R + 1>::run(win, a6, a3, a1);
  }
};
template <int T>
struct FmaR<T, RPT> {
  static __device__ __forceinline__ void run(const float (&)[WLEN],
                                             float (&)[RPT], float (&)[RPT], float (&)[RPT]) {}
};

// Load quad Q of this thread's window from the transposed LDS tile.
// colbase = &lds[c*NQS*4] (16B aligned); quad index = 4*ty + Q (compile-time Q).
template <int Q>
static __device__ __forceinline__ void load_quad(const float* __restrict__ colbase, int q0,
                                                 float (&win)[WLEN]) {
  const float4 v = *(const float4*)(colbase + ((q0 + Q) << 2));
  win[4 * Q + 0] = v.x; win[4 * Q + 1] = v.y; win[4 * Q + 2] = v.z; win[4 * Q + 3] = v.w;
}

template <int Q>
struct PreQ {
  static __device__ __forceinline__ void run(const float* __restrict__ colbase, int q0,
                                             float (&win)[WLEN]) {
    load_quad<Q>(colbase, q0, win);
    PreQ<Q + 1>::run(colbase, q0, win);
  }
};
template <>
struct PreQ<PQ> {
  static __device__ __forceinline__ void run(const float* __restrict__, int, float (&)[WLEN]) {}
};

template <int T>
struct Step {
  static __device__ __forceinline__ void run(const float* __restrict__ colbase, int q0,
                                             float (&win)[WLEN], float (&a6)[RPT],
                                             float (&a3)[RPT], float (&a1)[RPT]) {
    if constexpr ((T % 4 == 0) && (T / 4 + PQ < WQ))
      load_quad<T / 4 + PQ>(colbase, q0, win);
    FmaR<T, 0>::run(win, a6, a3, a1);
    Step<T + 1>::run(colbase, q0, win, a6, a3, a1);
  }
};
template <>
struct Step<62> {
  static __device__ __forceinline__ void run(const float* __restrict__, int, float (&)[WLEN],
                                             float (&)[RPT], float (&)[RPT], float (&)[RPT]) {}
};

template <int R>
struct Store {
  static __device__ __forceinline__ void run(float* __restrict__ o1, float* __restrict__ o3,
                                             float* __restrict__ o6, const float (&a6)[RPT],
                                             const float (&a3)[RPT], const float (&a1)[RPT]) {
    o1[(size_t)R * NCH] = a1[R];
    o3[(size_t)R * NCH] = a3[R];
    o6[(size_t)R * NCH] = a6[R];
    Store<R + 1>::run(o1, o3, o6, a6, a3, a1);
  }
};
template <>
struct Store<RPT> {
  static __device__ __forceinline__ void run(float* __restrict__, float* __restrict__,
                                             float* __restrict__, const float (&)[RPT],
                                             const float (&)[RPT], const float (&)[RPT]) {}
};

template <int R>
struct Zero {
  static __device__ __forceinline__ void run(float (&a6)[RPT], float (&a3)[RPT], float (&a1)[RPT]) {
    a6[R] = 0.f; a3[R] = 0.f; a1[R] = 0.f;
    Zero<R + 1>::run(a6, a3, a1);
  }
};
template <>
struct Zero<RPT> {
  static __device__ __forceinline__ void run(float (&)[RPT], float (&)[RPT], float (&)[RPT]) {}
};

__global__ __launch_bounds__(512, 6)
void cwt_main(const float* __restrict__ x, float* __restrict__ out) {
  // transposed tile: channel-major, 49-quad padded stride, 48 staged quads
  __shared__ __align__(16) float lds[NCH * NQS * 4];   // 50176 B -> 3 blocks/CU

  const int c  = threadIdx.x;         // 0..63 (lane = channel)
  const int ty = threadIdx.y;         // 0..7 (wave)

  // Bijective XCD swizzle (1024 % 8 == 0): 128 consecutive logical blocks per
  // XCD; consecutive sx tiles share 64 halo rows -> same-XCD L2 hits.
  const int hw = blockIdx.x;                  // 0..1023
  const int wg = ((hw & 7) << 7) + (hw >> 3);
  const int sx = wg & 31;                     // 32 s-tiles (fastest within XCD)
  const int b  = wg >> 5;                     // 32 signals
  const int s0 = sx * TILE_S;
  const int ROW0 = s0 - 32;                   // staged rows (quad-aligned halo)

  const float* __restrict__ xb = x + (size_t)b * S_LEN * NCH;

  // ---- stage 192 rows, transposed: lane=channel scalar loads (256B/wave,
  // coalesced), wave-uniform guards, then 6 ds_write_b128 per thread.
  {
    float pg[6][4];
    #pragma unroll
    for (int k = 0; k < 6; ++k) {
      #pragma unroll
      for (int j = 0; j < 4; ++j) {
        const int row = ROW0 + 24 * ty + 4 * k + j;   // wave-uniform
        float v = 0.f;
        if ((unsigned)row < (unsigned)S_LEN) v = xb[(size_t)row * NCH + c];
        pg[k][j] = v;
      }
    }
    #pragma unroll
    for (int k = 0; k < 6; ++k) {
      const int q = 6 * ty + k;
      *(float4*)&lds[c * (NQS * 4) + (q << 2)] =
          make_float4(pg[k][0], pg[k][1], pg[k][2], pg[k][3]);
    }
  }
  __syncthreads();

  // ---- sliding-window tap recursion; lgkmcnt traffic = ds_read_b128 ONLY
  const float* __restrict__ colbase = &lds[c * (NQS * 4)];
  const int q0 = 4 * ty;                      // thread's window start quad

  float win[WLEN];
  float a6[RPT], a3[RPT], a1[RPT];
  Zero<0>::run(a6, a3, a1);
  PreQ<0>::run(colbase, q0, win);             // quads 0..4 (20 rows)
  Step<0>::run(colbase, q0, win, a6, a3, a1); // taps 0..61, quad loads inline

  // ---- stores: 64 lanes x 4B contiguous per row; planes: 0=s1, 1=s3, 2=s6
  const int srow = s0 + RPT * ty;
  float* o1 = out + (((size_t)b * 3 + 0) * S_LEN + srow) * NCH + c;
  float* o3 = out + (((size_t)b * 3 + 1) * S_LEN + srow) * NCH + c;
  float* o6 = out + (((size_t)b * 3 + 2) * S_LEN + srow) * NCH + c;
  Store<0>::run(o1, o3, o6, a6, a3, a1);
}

extern "C" void kernel_launch(void* const* d_in, const int* in_sizes, int n_in,
                              void* d_out, int out_size, void* d_ws, size_t ws_size,
                              hipStream_t stream) {
  (void)n_in; (void)out_size; (void)d_ws; (void)ws_size;
  const float* x = (const float*)d_in[0];
  float* out = (float*)d_out;
  const int B = in_sizes[0] / (S_LEN * NCH);   // 32

  const int nblk = (S_LEN / TILE_S) * B;       // 32 * 32 = 1024 (div by 8)
  dim3 grid(nblk);
  dim3 block(NCH, TY);                         // 512 threads = 8 waves
  hipLaunchKernelGGL(cwt_main, grid, block, 0, stream, x, out);
}